// Round 21
// baseline (106.425 us; speedup 1.0000x reference)
//
#include <hip/hip_runtime.h>

#define B_ 2
#define S_ 2048
#define F_ 1024
#define H_ 16
#define D_ 64

typedef __bf16 bf16x8 __attribute__((ext_vector_type(8)));
typedef float f32x4 __attribute__((ext_vector_type(4)));
typedef float f32x16 __attribute__((ext_vector_type(16)));

union U8 { unsigned int u[4]; bf16x8 v; };

__device__ __forceinline__ unsigned short f2bf(float f) {
    union { float f; unsigned int u; } v;
    v.f = f;
    unsigned int r = v.u + 0x7fffu + ((v.u >> 16) & 1u);
    return (unsigned short)(r >> 16);
}

__device__ __forceinline__ unsigned int cvtpk_bf16(float lo, float hi) {
    unsigned int r;
    asm("v_cvt_pk_bf16_f32 %0, %1, %2" : "=v"(r) : "v"(lo), "v"(hi));
    return r;
}

__device__ __forceinline__ float xhalf_sum(float x) {
    return x + __shfl_xor(x, 32);
}

// async global->LDS, 16B per lane. LDS dest must be wave-uniform base + lane*16.
__device__ __forceinline__ void gload16(const unsigned short* g, unsigned short* l) {
    __builtin_amdgcn_global_load_lds(
        (const __attribute__((address_space(1))) unsigned int*)g,
        (__attribute__((address_space(3))) unsigned int*)l,
        16, 0, 0);
}

// ---------- fused prep: x cvt (blocks 0-4095), w_attn tcvt (4096-7167), w_proj tcvt (7168-8191) ----------
__global__ __launch_bounds__(256) void prep_kernel(const float* __restrict__ x, unsigned short* __restrict__ xb,
                                                   const float* __restrict__ wa, unsigned short* __restrict__ wat,
                                                   const float* __restrict__ wp, unsigned short* __restrict__ wpt) {
    __shared__ float t[32][33];
    int bid = blockIdx.x, tid = threadIdx.x;
    if (bid < 4096) {
        int i = bid * 256 + tid;
        float4 v = reinterpret_cast<const float4*>(x)[i];
        ushort4 o;
        o.x = f2bf(v.x); o.y = f2bf(v.y); o.z = f2bf(v.z); o.w = f2bf(v.w);
        reinterpret_cast<ushort4*>(xb)[i] = o;
        return;
    }
    const float* in;
    unsigned short* out;
    int R, C, bx, by;
    if (bid < 7168) {
        int loc = bid - 4096;
        bx = loc % 96; by = loc / 96;
        in = wa; out = wat; R = 1024; C = 3072;
    } else {
        int loc = bid - 7168;
        bx = loc & 31; by = loc >> 5;
        in = wp; out = wpt; R = 1024; C = 1024;
    }
    int tx = tid & 31, ty = tid >> 5;
    int r0 = by << 5, c0 = bx << 5;
#pragma unroll
    for (int kk = 0; kk < 4; ++kk)
        t[ty + 8 * kk][tx] = in[(size_t)(r0 + ty + 8 * kk) * C + c0 + tx];
    __syncthreads();
#pragma unroll
    for (int kk = 0; kk < 4; ++kk)
        out[(size_t)(c0 + ty + 8 * kk) * R + r0 + tx] = f2bf(t[tx][ty + 8 * kk]);
}

// ---------- GEMM1: qkv = x @ w_attn + b_attn (256x256 8-wave, R15-proven) ----------
__global__ __launch_bounds__(512, 2) void gemm_qkv(const unsigned short* __restrict__ A,
                                                   const unsigned short* __restrict__ Bt,
                                                   const float* __restrict__ bias,
                                                   unsigned short* __restrict__ qo,
                                                   unsigned short* __restrict__ ko,
                                                   unsigned short* __restrict__ vo) {
    __shared__ __align__(16) unsigned short lds[65536];   // 128 KB
    const int K = 1024;
    int bid = blockIdx.x;
    int swz = (bid & 7) * 24 + (bid >> 3);
    int by = swz / 12, bx = swz % 12;
    int m0 = by << 8, n0 = bx << 8;
    int tid = threadIdx.x;
    int wid = tid >> 6, l = tid & 63, lg = l >> 4, lr = l & 15;
    int wr = wid >> 2, wc = wid & 3;
    f32x4 acc[8][4] = {};

    int g0 = tid, g1 = tid + 512;
    int r0 = g0 >> 3, p0 = g0 & 7;
    int r1 = g1 >> 3, p1 = g1 & 7;
    int c0 = (p0 ^ (r0 & 7)) << 3;
    int c1 = (p1 ^ (r1 & 7)) << 3;

    int xr = (lr & 7) << 3;
    int csw0 = (lg * 8) ^ xr;
    int csw1 = (32 + lg * 8) ^ xr;

    const unsigned short* A0 = A + (size_t)(m0 + r0) * K + c0;
    const unsigned short* A1 = A + (size_t)(m0 + r1) * K + c1;
    const unsigned short* A2 = A + (size_t)(m0 + 128 + r0) * K + c0;
    const unsigned short* A3 = A + (size_t)(m0 + 128 + r1) * K + c1;
    const unsigned short* B0 = Bt + (size_t)(n0 + r0) * K + c0;
    const unsigned short* B1 = Bt + (size_t)(n0 + r1) * K + c1;
    const unsigned short* B2 = Bt + (size_t)(n0 + 128 + r0) * K + c0;
    const unsigned short* B3 = Bt + (size_t)(n0 + 128 + r1) * K + c1;

    gload16(A0, &lds[g0 * 8]);
    gload16(A1, &lds[g1 * 8]);
    gload16(A2, &lds[8192 + g0 * 8]);
    gload16(A3, &lds[8192 + g1 * 8]);
    gload16(B0, &lds[16384 + g0 * 8]);
    gload16(B1, &lds[16384 + g1 * 8]);
    gload16(B2, &lds[24576 + g0 * 8]);
    gload16(B3, &lds[24576 + g1 * 8]);
    __syncthreads();

    for (int t = 0; t < 16; ++t) {
        int bo = (t & 1) * 32768;
        if (t < 15) {
            int no = ((t + 1) & 1) * 32768;
            int t64 = (t + 1) * 64;
            gload16(A0 + t64, &lds[no + g0 * 8]);
            gload16(A1 + t64, &lds[no + g1 * 8]);
            gload16(A2 + t64, &lds[no + 8192 + g0 * 8]);
            gload16(A3 + t64, &lds[no + 8192 + g1 * 8]);
            gload16(B0 + t64, &lds[no + 16384 + g0 * 8]);
            gload16(B1 + t64, &lds[no + 16384 + g1 * 8]);
            gload16(B2 + t64, &lds[no + 24576 + g0 * 8]);
            gload16(B3 + t64, &lds[no + 24576 + g1 * 8]);
        }
        bf16x8 Bf[8];
#pragma unroll
        for (int ni = 0; ni < 4; ++ni) {
            int rowB = wc * 64 + ni * 16 + lr;
            int ba = bo + 16384 + (rowB >> 7) * 8192 + (rowB & 127) * 64;
            Bf[ni * 2]     = *reinterpret_cast<const bf16x8*>(&lds[ba + csw0]);
            Bf[ni * 2 + 1] = *reinterpret_cast<const bf16x8*>(&lds[ba + csw1]);
        }
#pragma unroll
        for (int mi = 0; mi < 8; ++mi) {
            int aa = bo + wr * 8192 + (mi * 16 + lr) * 64;
            bf16x8 a0 = *reinterpret_cast<const bf16x8*>(&lds[aa + csw0]);
            bf16x8 a1 = *reinterpret_cast<const bf16x8*>(&lds[aa + csw1]);
#pragma unroll
            for (int ni = 0; ni < 4; ++ni) {
                acc[mi][ni] = __builtin_amdgcn_mfma_f32_16x16x32_bf16(a0, Bf[ni * 2], acc[mi][ni], 0, 0, 0);
                acc[mi][ni] = __builtin_amdgcn_mfma_f32_16x16x32_bf16(a1, Bf[ni * 2 + 1], acc[mi][ni], 0, 0, 0);
            }
        }
        __syncthreads();
    }

#pragma unroll
    for (int mi = 0; mi < 8; ++mi) {
#pragma unroll
        for (int ni = 0; ni < 4; ++ni) {
            int col = n0 + wc * 64 + ni * 16 + lr;
            float bv = bias[col];
            int part = col >> 10, cc = col & 1023, h = cc >> 6, d = cc & 63;
            int row0 = m0 + wr * 128 + mi * 16 + (lg << 2);
            int bb = row0 >> 11, s0 = row0 & 2047;
            int bh = bb * H_ + h;
            if (part == 2) {
                int jt = s0 >> 5, db = d >> 5, kf2 = (s0 >> 4) & 1, hi2 = (s0 >> 3) & 1;
                int ll = (d & 31) | (hi2 << 5), e0 = s0 & 7;
                ushort4 pk;
                unsigned short* p = reinterpret_cast<unsigned short*>(&pk);
#pragma unroll
                for (int r = 0; r < 4; ++r) p[r] = f2bf(acc[mi][ni][r] + bv);
                *reinterpret_cast<ushort4*>(
                    &vo[(size_t)((((bh * 64 + jt) * 2 + db) * 2 + kf2)) * 512 + ll * 8 + e0]) = pk;
            } else {
                unsigned short* dst = part == 0 ? qo : ko;
                float scale = part == 0 ? 0.125f * 1.44269504f : 1.0f;
                int t2 = s0 >> 5, kf2 = d >> 4, e = d & 7;
                int lbase = ((d >> 3) & 1) << 5;
                size_t fb = (size_t)((bh * 64 + t2) * 4 + kf2) * 512 + e;
#pragma unroll
                for (int r = 0; r < 4; ++r) {
                    float vv = (acc[mi][ni][r] + bv) * scale;
                    dst[fb + (size_t)((((s0 + r) & 31) | lbase)) * 8] = f2bf(vv);
                }
            }
        }
    }
}

// ---------- GEMM2: out = z @ w_proj + b_proj (f32 out) ----------
// BK=64 2-phase: 16 K-steps, 32 MFMA/wave per barrier (2x amortization vs BK=32),
// R15-proven XOR swizzle (each 128x64 tile == one R15 "half"; same involution).
__global__ __launch_bounds__(256) void gemm_proj(const unsigned short* __restrict__ A,
                                                 const unsigned short* __restrict__ Bt,
                                                 const float* __restrict__ bias,
                                                 float* __restrict__ out) {
    __shared__ __align__(16) unsigned short As[2 * 128 * 64];   // 32 KB x2
    __shared__ __align__(16) unsigned short Bs[2 * 128 * 64];
    const int K = 1024, NT = 16;
    int m0 = blockIdx.y << 7, n0 = blockIdx.x << 7;
    int tid = threadIdx.x;
    int w = tid >> 6, l = tid & 63, lg = l >> 4, lr = l & 15;
    int wm = (w >> 1) << 6, wn = (w & 1) << 6;
    f32x4 acc[4][4] = {};

    // staging: 4 granules (16B) per matrix per thread; granule g -> row g>>3, pos g&7
    int g0 = tid, g1 = tid + 256, g2 = tid + 512, g3 = tid + 768;
    int r0 = g0 >> 3, p0 = g0 & 7;
    int r1 = g1 >> 3, p1 = g1 & 7;
    int r2 = g2 >> 3, p2 = g2 & 7;
    int r3 = g3 >> 3, p3 = g3 & 7;
    int c0 = (p0 ^ (r0 & 7)) << 3;   // pre-swizzled source col
    int c1 = (p1 ^ (r1 & 7)) << 3;
    int c2 = (p2 ^ (r2 & 7)) << 3;
    int c3 = (p3 ^ (r3 & 7)) << 3;

    int xr = (lr & 7) << 3;
    int csw0 = (lg * 8) ^ xr;        // kk = 0 (cols 0-31)
    int csw1 = (32 + lg * 8) ^ xr;   // kk = 1 (cols 32-63)

    const unsigned short* A0 = A + (size_t)(m0 + r0) * K + c0;
    const unsigned short* A1 = A + (size_t)(m0 + r1) * K + c1;
    const unsigned short* A2 = A + (size_t)(m0 + r2) * K + c2;
    const unsigned short* A3 = A + (size_t)(m0 + r3) * K + c3;
    const unsigned short* B0 = Bt + (size_t)(n0 + r0) * K + c0;
    const unsigned short* B1 = Bt + (size_t)(n0 + r1) * K + c1;
    const unsigned short* B2 = Bt + (size_t)(n0 + r2) * K + c2;
    const unsigned short* B3 = Bt + (size_t)(n0 + r3) * K + c3;

    // prologue: stage K-step 0 into buffer 0
    gload16(A0, &As[g0 * 8]);
    gload16(A1, &As[g1 * 8]);
    gload16(A2, &As[g2 * 8]);
    gload16(A3, &As[g3 * 8]);
    gload16(B0, &Bs[g0 * 8]);
    gload16(B1, &Bs[g1 * 8]);
    gload16(B2, &Bs[g2 * 8]);
    gload16(B3, &Bs[g3 * 8]);
    __syncthreads();

    for (int t = 0; t < NT; ++t) {
        int cur = (t & 1) * 8192;
        if (t + 1 < NT) {
            int nxt = ((t + 1) & 1) * 8192;
            int ko2 = (t + 1) * 64;
            gload16(A0 + ko2, &As[nxt + g0 * 8]);
            gload16(A1 + ko2, &As[nxt + g1 * 8]);
            gload16(A2 + ko2, &As[nxt + g2 * 8]);
            gload16(A3 + ko2, &As[nxt + g3 * 8]);
            gload16(B0 + ko2, &Bs[nxt + g0 * 8]);
            gload16(B1 + ko2, &Bs[nxt + g1 * 8]);
            gload16(B2 + ko2, &Bs[nxt + g2 * 8]);
            gload16(B3 + ko2, &Bs[nxt + g3 * 8]);
        }
        bf16x8 Bf[8];
#pragma unroll
        for (int ni = 0; ni < 4; ++ni) {
            int ba = cur + (wn + ni * 16 + lr) * 64;
            Bf[ni * 2]     = *reinterpret_cast<const bf16x8*>(&Bs[ba + csw0]);
            Bf[ni * 2 + 1] = *reinterpret_cast<const bf16x8*>(&Bs[ba + csw1]);
        }
#pragma unroll
        for (int mi = 0; mi < 4; ++mi) {
            int aa = cur + (wm + mi * 16 + lr) * 64;
            bf16x8 a0 = *reinterpret_cast<const bf16x8*>(&As[aa + csw0]);
            bf16x8 a1 = *reinterpret_cast<const bf16x8*>(&As[aa + csw1]);
#pragma unroll
            for (int ni = 0; ni < 4; ++ni) {
                acc[mi][ni] = __builtin_amdgcn_mfma_f32_16x16x32_bf16(a0, Bf[ni * 2], acc[mi][ni], 0, 0, 0);
                acc[mi][ni] = __builtin_amdgcn_mfma_f32_16x16x32_bf16(a1, Bf[ni * 2 + 1], acc[mi][ni], 0, 0, 0);
            }
        }
        __syncthreads();
    }
#pragma unroll
    for (int mi = 0; mi < 4; ++mi) {
#pragma unroll
        for (int ni = 0; ni < 4; ++ni) {
            int col = n0 + wn + ni * 16 + lr;
            float bv = bias[col];
#pragma unroll
            for (int r = 0; r < 4; ++r) {
                int row = m0 + wm + mi * 16 + (lg << 2) + r;
                out[(size_t)row * F_ + col] = acc[mi][ni][r] + bv;
            }
        }
    }
}

// ---------- attention 32x32 tile: NO-MAX softmax (R16-proven) ----------
__device__ __forceinline__ void attn_tile32(
    const unsigned short* __restrict__ k, const unsigned short* __restrict__ v,
    int bh, int jt, bool pref, bool diag, int qcol, int hi, size_t lofs,
    const bf16x8 (&qf)[4], bf16x8 (&kcur)[4], bf16x8 (&knxt)[4],
    float &lsum, f32x16 &ot0, f32x16 &ot1)
{
    bf16x8 vf[4];
    const unsigned short* vp = v + (size_t)(bh * 64 + jt) * 2048 + lofs;
#pragma unroll
    for (int i = 0; i < 4; ++i)
        vf[i] = *reinterpret_cast<const bf16x8*>(vp + i * 512);
    if (pref) {
        const unsigned short* kp = k + (size_t)(bh * 64 + jt + 1) * 2048 + lofs;
#pragma unroll
        for (int kf = 0; kf < 4; ++kf)
            knxt[kf] = *reinterpret_cast<const bf16x8*>(kp + kf * 512);
    }

    f32x16 st = {};
#pragma unroll
    for (int kf = 0; kf < 4; ++kf)
        st = __builtin_amdgcn_mfma_f32_32x32x16_bf16(kcur[kf], qf[kf], st, 0, 0, 0);

    if (diag) {
        int qmh = qcol - 4 * hi;
#pragma unroll
        for (int r = 0; r < 16; ++r) {
            const int kbase = (r & 3) + 8 * (r >> 2);
            st[r] = (kbase > qmh) ? -1e30f : st[r];
        }
    }

    float ps = 0.f;
#pragma unroll
    for (int r = 0; r < 16; ++r) { st[r] = exp2f(st[r]); ps += st[r]; }
    lsum += ps;

    U8 pa0, pa1;
#pragma unroll
    for (int f = 0; f < 2; ++f) {
        unsigned int a0 = cvtpk_bf16(st[f * 8 + 0], st[f * 8 + 1]);
        unsigned int b0 = cvtpk_bf16(st[f * 8 + 4], st[f * 8 + 5]);
        asm("v_permlane32_swap_b32 %0, %1" : "+v"(a0), "+v"(b0));
        unsigned int a1 = cvtpk_bf16(st[f * 8 + 2], st[f * 8 + 3]);
        unsigned int b1 = cvtpk_bf16(st[f * 8 + 6], st[f * 8 + 7]);
        asm("v_permlane32_swap_b32 %0, %1" : "+v"(a1), "+v"(b1));
        U8& pa = f ? pa1 : pa0;
        pa.u[0] = a0; pa.u[1] = a1; pa.u[2] = b0; pa.u[3] = b1;
    }

    ot0 = __builtin_amdgcn_mfma_f32_32x32x16_bf16(vf[0], pa0.v, ot0, 0, 0, 0);
    ot0 = __builtin_amdgcn_mfma_f32_32x32x16_bf16(vf[1], pa1.v, ot0, 0, 0, 0);
    ot1 = __builtin_amdgcn_mfma_f32_32x32x16_bf16(vf[2], pa0.v, ot1, 0, 0, 0);
    ot1 = __builtin_amdgcn_mfma_f32_32x32x16_bf16(vf[3], pa1.v, ot1, 0, 0, 0);
}

// ---------- causal flash attention: 4-wave block, 4-way split-K, pure-sum merge ----------
// (256,3): live set ~120-130 VGPR needs the ~170 cap. THREE measured spill regressions
// (R5, R17, R19) prove any +32-VGPR structural change or higher occupancy bound spills.
__global__ __launch_bounds__(256, 3) void attn_kernel(const unsigned short* __restrict__ q,
                                                      const unsigned short* __restrict__ k,
                                                      const unsigned short* __restrict__ v,
                                                      unsigned short* __restrict__ z) {
    __shared__ __align__(16) float mbuf[3][64][36];
    int bh = blockIdx.x;
    int qt = gridDim.y - 1 - blockIdx.y;
    int q0 = qt << 5;
    int tid = threadIdx.x, w = tid >> 6, l = tid & 63;
    int qcol = l & 31, hi = l >> 5;
    size_t lofs = (size_t)l * 8;

    bf16x8 qf[4];
    {
        const unsigned short* qp = q + (size_t)(bh * 64 + qt) * 2048 + lofs;
#pragma unroll
        for (int kf = 0; kf < 4; ++kf)
            qf[kf] = *reinterpret_cast<const bf16x8*>(qp + kf * 512);
    }

    f32x16 ot0 = {}, ot1 = {};
    float lsum = 0.f;

    int ntk = qt + 1;
    int bs = ntk >> 2, rem = ntk & 3;
    int cnt = bs + ((w >= 4 - rem) ? 1 : 0);
    int start = bs * w + ((w - (4 - rem)) > 0 ? (w - (4 - rem)) : 0);
    int end = start + cnt;

    if (cnt > 0) {
        bf16x8 kA[4], kB[4];
        const unsigned short* kp = k + (size_t)(bh * 64 + start) * 2048 + lofs;
#pragma unroll
        for (int kf = 0; kf < 4; ++kf)
            kA[kf] = *reinterpret_cast<const bf16x8*>(kp + kf * 512);

        int jt = start;
        for (;;) {
            attn_tile32(k, v, bh, jt, jt + 1 < end, jt == qt, qcol, hi, lofs,
                        qf, kA, kB, lsum, ot0, ot1);
            if (++jt >= end) break;
            attn_tile32(k, v, bh, jt, jt + 1 < end, jt == qt, qcol, hi, lofs,
                        qf, kB, kA, lsum, ot0, ot1);
            if (++jt >= end) break;
        }
    }

    lsum = xhalf_sum(lsum);

    if (w) {
        float* row = mbuf[w - 1][l];
        row[0] = lsum;
        *reinterpret_cast<f32x16*>(&row[4]) = ot0;
        *reinterpret_cast<f32x16*>(&row[20]) = ot1;
    }
    __syncthreads();
    if (w == 0) {
#pragma unroll
        for (int i = 0; i < 3; ++i) {
            lsum += mbuf[i][l][0];
            f32x16 t0 = *reinterpret_cast<const f32x16*>(&mbuf[i][l][4]);
            f32x16 t1 = *reinterpret_cast<const f32x16*>(&mbuf[i][l][20]);
            ot0 += t0;
            ot1 += t1;
        }

        float inv = 1.0f / lsum;
        int b = bh >> 4, h = bh & 15;
        size_t zrow = ((size_t)(b * S_ + q0 + qcol)) * F_ + h * D_;
#pragma unroll
        for (int db = 0; db < 2; ++db) {
#pragma unroll
            for (int rq = 0; rq < 4; ++rq) {
                ushort4 pk;
                unsigned short* pp = reinterpret_cast<unsigned short*>(&pk);
#pragma unroll
                for (int i = 0; i < 4; ++i) {
                    float val = (db == 0 ? ot0[rq * 4 + i] : ot1[rq * 4 + i]) * inv;
                    pp[i] = f2bf(val);
                }
                *reinterpret_cast<ushort4*>(&z[zrow + db * 32 + rq * 8 + hi * 4]) = pk;
            }
        }
    }
}

extern "C" void kernel_launch(void* const* d_in, const int* in_sizes, int n_in,
                              void* d_out, int out_size, void* d_ws, size_t ws_size,
                              hipStream_t stream) {
    const float* x      = (const float*)d_in[0];
    const float* w_attn = (const float*)d_in[1];
    const float* b_attn = (const float*)d_in[2];
    const float* w_proj = (const float*)d_in[3];
    const float* b_proj = (const float*)d_in[4];
    float* out = (float*)d_out;
    char* ws = (char*)d_ws;

    unsigned short* xb   = (unsigned short*)(ws);              // [4096][1024] bf16, reused as z
    unsigned short* wa_t = (unsigned short*)(ws + 8388608);    // [3072][1024]
    unsigned short* wp_t = (unsigned short*)(ws + 14680064);   // [1024][1024]
    unsigned short* qb   = (unsigned short*)(ws + 16777216);   // fragment-major Q (pre-scaled)
    unsigned short* kb   = (unsigned short*)(ws + 25165824);   // fragment-major K
    unsigned short* vb   = (unsigned short*)(ws + 33554432);   // fragment-major V
    unsigned short* zb   = xb;                                 // alias: x consumed by gemm_qkv

    prep_kernel<<<8192, 256, 0, stream>>>(x, xb, w_attn, wa_t, w_proj, wp_t);
    gemm_qkv<<<192, 512, 0, stream>>>(xb, wa_t, b_attn, qb, kb, vb);
    attn_kernel<<<dim3(32, 64), 256, 0, stream>>>(qb, kb, vb, zb);
    gemm_proj<<<dim3(8, 32), 256, 0, stream>>>(zb, wp_t, b_proj, out);
}

// Round 22
// 105.130 us; speedup vs baseline: 1.0123x; 1.0123x over previous
//
#include <hip/hip_runtime.h>

#define B_ 2
#define S_ 2048
#define F_ 1024
#define H_ 16
#define D_ 64

typedef __bf16 bf16x8 __attribute__((ext_vector_type(8)));
typedef float f32x4 __attribute__((ext_vector_type(4)));
typedef float f32x16 __attribute__((ext_vector_type(16)));

union U8 { unsigned int u[4]; bf16x8 v; };

__device__ __forceinline__ unsigned short f2bf(float f) {
    union { float f; unsigned int u; } v;
    v.f = f;
    unsigned int r = v.u + 0x7fffu + ((v.u >> 16) & 1u);
    return (unsigned short)(r >> 16);
}

__device__ __forceinline__ unsigned int cvtpk_bf16(float lo, float hi) {
    unsigned int r;
    asm("v_cvt_pk_bf16_f32 %0, %1, %2" : "=v"(r) : "v"(lo), "v"(hi));
    return r;
}

__device__ __forceinline__ float xhalf_sum(float x) {
    return x + __shfl_xor(x, 32);
}

// async global->LDS, 16B per lane. LDS dest must be wave-uniform base + lane*16.
__device__ __forceinline__ void gload16(const unsigned short* g, unsigned short* l) {
    __builtin_amdgcn_global_load_lds(
        (const __attribute__((address_space(1))) unsigned int*)g,
        (__attribute__((address_space(3))) unsigned int*)l,
        16, 0, 0);
}

// ---------- fused prep: x cvt (blocks 0-4095), w_attn tcvt (4096-7167), w_proj tcvt (7168-8191) ----------
__global__ __launch_bounds__(256) void prep_kernel(const float* __restrict__ x, unsigned short* __restrict__ xb,
                                                   const float* __restrict__ wa, unsigned short* __restrict__ wat,
                                                   const float* __restrict__ wp, unsigned short* __restrict__ wpt) {
    __shared__ float t[32][33];
    int bid = blockIdx.x, tid = threadIdx.x;
    if (bid < 4096) {
        int i = bid * 256 + tid;
        float4 v = reinterpret_cast<const float4*>(x)[i];
        ushort4 o;
        o.x = f2bf(v.x); o.y = f2bf(v.y); o.z = f2bf(v.z); o.w = f2bf(v.w);
        reinterpret_cast<ushort4*>(xb)[i] = o;
        return;
    }
    const float* in;
    unsigned short* out;
    int R, C, bx, by;
    if (bid < 7168) {
        int loc = bid - 4096;
        bx = loc % 96; by = loc / 96;
        in = wa; out = wat; R = 1024; C = 3072;
    } else {
        int loc = bid - 7168;
        bx = loc & 31; by = loc >> 5;
        in = wp; out = wpt; R = 1024; C = 1024;
    }
    int tx = tid & 31, ty = tid >> 5;
    int r0 = by << 5, c0 = bx << 5;
#pragma unroll
    for (int kk = 0; kk < 4; ++kk)
        t[ty + 8 * kk][tx] = in[(size_t)(r0 + ty + 8 * kk) * C + c0 + tx];
    __syncthreads();
#pragma unroll
    for (int kk = 0; kk < 4; ++kk)
        out[(size_t)(c0 + ty + 8 * kk) * R + r0 + tx] = f2bf(t[tx][ty + 8 * kk]);
}

// ---------- GEMM1: qkv = x @ w_attn + b_attn (256x256 8-wave, R15-proven) ----------
__global__ __launch_bounds__(512, 2) void gemm_qkv(const unsigned short* __restrict__ A,
                                                   const unsigned short* __restrict__ Bt,
                                                   const float* __restrict__ bias,
                                                   unsigned short* __restrict__ qo,
                                                   unsigned short* __restrict__ ko,
                                                   unsigned short* __restrict__ vo) {
    __shared__ __align__(16) unsigned short lds[65536];   // 128 KB
    const int K = 1024;
    int bid = blockIdx.x;
    int swz = (bid & 7) * 24 + (bid >> 3);
    int by = swz / 12, bx = swz % 12;
    int m0 = by << 8, n0 = bx << 8;
    int tid = threadIdx.x;
    int wid = tid >> 6, l = tid & 63, lg = l >> 4, lr = l & 15;
    int wr = wid >> 2, wc = wid & 3;
    f32x4 acc[8][4] = {};

    int g0 = tid, g1 = tid + 512;
    int r0 = g0 >> 3, p0 = g0 & 7;
    int r1 = g1 >> 3, p1 = g1 & 7;
    int c0 = (p0 ^ (r0 & 7)) << 3;
    int c1 = (p1 ^ (r1 & 7)) << 3;

    int xr = (lr & 7) << 3;
    int csw0 = (lg * 8) ^ xr;
    int csw1 = (32 + lg * 8) ^ xr;

    const unsigned short* A0 = A + (size_t)(m0 + r0) * K + c0;
    const unsigned short* A1 = A + (size_t)(m0 + r1) * K + c1;
    const unsigned short* A2 = A + (size_t)(m0 + 128 + r0) * K + c0;
    const unsigned short* A3 = A + (size_t)(m0 + 128 + r1) * K + c1;
    const unsigned short* B0 = Bt + (size_t)(n0 + r0) * K + c0;
    const unsigned short* B1 = Bt + (size_t)(n0 + r1) * K + c1;
    const unsigned short* B2 = Bt + (size_t)(n0 + 128 + r0) * K + c0;
    const unsigned short* B3 = Bt + (size_t)(n0 + 128 + r1) * K + c1;

    gload16(A0, &lds[g0 * 8]);
    gload16(A1, &lds[g1 * 8]);
    gload16(A2, &lds[8192 + g0 * 8]);
    gload16(A3, &lds[8192 + g1 * 8]);
    gload16(B0, &lds[16384 + g0 * 8]);
    gload16(B1, &lds[16384 + g1 * 8]);
    gload16(B2, &lds[24576 + g0 * 8]);
    gload16(B3, &lds[24576 + g1 * 8]);
    __syncthreads();

    for (int t = 0; t < 16; ++t) {
        int bo = (t & 1) * 32768;
        if (t < 15) {
            int no = ((t + 1) & 1) * 32768;
            int t64 = (t + 1) * 64;
            gload16(A0 + t64, &lds[no + g0 * 8]);
            gload16(A1 + t64, &lds[no + g1 * 8]);
            gload16(A2 + t64, &lds[no + 8192 + g0 * 8]);
            gload16(A3 + t64, &lds[no + 8192 + g1 * 8]);
            gload16(B0 + t64, &lds[no + 16384 + g0 * 8]);
            gload16(B1 + t64, &lds[no + 16384 + g1 * 8]);
            gload16(B2 + t64, &lds[no + 24576 + g0 * 8]);
            gload16(B3 + t64, &lds[no + 24576 + g1 * 8]);
        }
        bf16x8 Bf[8];
#pragma unroll
        for (int ni = 0; ni < 4; ++ni) {
            int rowB = wc * 64 + ni * 16 + lr;
            int ba = bo + 16384 + (rowB >> 7) * 8192 + (rowB & 127) * 64;
            Bf[ni * 2]     = *reinterpret_cast<const bf16x8*>(&lds[ba + csw0]);
            Bf[ni * 2 + 1] = *reinterpret_cast<const bf16x8*>(&lds[ba + csw1]);
        }
#pragma unroll
        for (int mi = 0; mi < 8; ++mi) {
            int aa = bo + wr * 8192 + (mi * 16 + lr) * 64;
            bf16x8 a0 = *reinterpret_cast<const bf16x8*>(&lds[aa + csw0]);
            bf16x8 a1 = *reinterpret_cast<const bf16x8*>(&lds[aa + csw1]);
#pragma unroll
            for (int ni = 0; ni < 4; ++ni) {
                acc[mi][ni] = __builtin_amdgcn_mfma_f32_16x16x32_bf16(a0, Bf[ni * 2], acc[mi][ni], 0, 0, 0);
                acc[mi][ni] = __builtin_amdgcn_mfma_f32_16x16x32_bf16(a1, Bf[ni * 2 + 1], acc[mi][ni], 0, 0, 0);
            }
        }
        __syncthreads();
    }

#pragma unroll
    for (int mi = 0; mi < 8; ++mi) {
#pragma unroll
        for (int ni = 0; ni < 4; ++ni) {
            int col = n0 + wc * 64 + ni * 16 + lr;
            float bv = bias[col];
            int part = col >> 10, cc = col & 1023, h = cc >> 6, d = cc & 63;
            int row0 = m0 + wr * 128 + mi * 16 + (lg << 2);
            int bb = row0 >> 11, s0 = row0 & 2047;
            int bh = bb * H_ + h;
            if (part == 2) {
                int jt = s0 >> 5, db = d >> 5, kf2 = (s0 >> 4) & 1, hi2 = (s0 >> 3) & 1;
                int ll = (d & 31) | (hi2 << 5), e0 = s0 & 7;
                ushort4 pk;
                unsigned short* p = reinterpret_cast<unsigned short*>(&pk);
#pragma unroll
                for (int r = 0; r < 4; ++r) p[r] = f2bf(acc[mi][ni][r] + bv);
                *reinterpret_cast<ushort4*>(
                    &vo[(size_t)((((bh * 64 + jt) * 2 + db) * 2 + kf2)) * 512 + ll * 8 + e0]) = pk;
            } else {
                unsigned short* dst = part == 0 ? qo : ko;
                float scale = part == 0 ? 0.125f * 1.44269504f : 1.0f;
                int t2 = s0 >> 5, kf2 = d >> 4, e = d & 7;
                int lbase = ((d >> 3) & 1) << 5;
                size_t fb = (size_t)((bh * 64 + t2) * 4 + kf2) * 512 + e;
#pragma unroll
                for (int r = 0; r < 4; ++r) {
                    float vv = (acc[mi][ni][r] + bv) * scale;
                    dst[fb + (size_t)((((s0 + r) & 31) | lbase)) * 8] = f2bf(vv);
                }
            }
        }
    }
}

// ---------- GEMM2: out = z @ w_proj + b_proj (f32 out; 2-phase pipelined; R10-proven) ----------
__global__ __launch_bounds__(256) void gemm_proj(const unsigned short* __restrict__ A,
                                                 const unsigned short* __restrict__ Bt,
                                                 const float* __restrict__ bias,
                                                 float* __restrict__ out) {
    __shared__ __align__(16) unsigned short As[2 * 128 * 32];
    __shared__ __align__(16) unsigned short Bs[2 * 128 * 32];
    const int K = 1024, NT = 32;
    int m0 = blockIdx.y << 7, n0 = blockIdx.x << 7;
    int tid = threadIdx.x;
    int w = tid >> 6, l = tid & 63, lg = l >> 4, lr = l & 15;
    int wm = (w >> 1) << 6, wn = (w & 1) << 6;
    f32x4 acc[4][4] = {};

    int sr = tid >> 2, sc = (tid & 3) << 3;
    const unsigned short* Ab = A + (size_t)(m0 + sr) * K + sc;
    const unsigned short* Bb = Bt + (size_t)(n0 + sr) * K + sc;
    const size_t half = (size_t)64 * K;

    gload16(Ab, &As[tid * 8]);
    gload16(Ab + half, &As[2048 + tid * 8]);
    gload16(Bb, &Bs[tid * 8]);
    gload16(Bb + half, &Bs[2048 + tid * 8]);
    __syncthreads();

    for (int t = 0; t < NT; ++t) {
        int cur = (t & 1) * 4096;
        if (t + 1 < NT) {
            int nxt = ((t + 1) & 1) * 4096;
            int ko2 = (t + 1) * 32;
            gload16(Ab + ko2, &As[nxt + tid * 8]);
            gload16(Ab + ko2 + half, &As[nxt + 2048 + tid * 8]);
            gload16(Bb + ko2, &Bs[nxt + tid * 8]);
            gload16(Bb + ko2 + half, &Bs[nxt + 2048 + tid * 8]);
        }
        bf16x8 af[4], bfr[4];
#pragma unroll
        for (int mi = 0; mi < 4; ++mi)
            af[mi] = *reinterpret_cast<const bf16x8*>(&As[cur + (wm + mi * 16 + lr) * 32 + (lg << 3)]);
#pragma unroll
        for (int ni = 0; ni < 4; ++ni)
            bfr[ni] = *reinterpret_cast<const bf16x8*>(&Bs[cur + (wn + ni * 16 + lr) * 32 + (lg << 3)]);
#pragma unroll
        for (int mi = 0; mi < 4; ++mi)
#pragma unroll
            for (int ni = 0; ni < 4; ++ni)
                acc[mi][ni] = __builtin_amdgcn_mfma_f32_16x16x32_bf16(af[mi], bfr[ni], acc[mi][ni], 0, 0, 0);
        __syncthreads();
    }
#pragma unroll
    for (int mi = 0; mi < 4; ++mi) {
#pragma unroll
        for (int ni = 0; ni < 4; ++ni) {
            int col = n0 + wn + ni * 16 + lr;
            float bv = bias[col];
#pragma unroll
            for (int r = 0; r < 4; ++r) {
                int row = m0 + wm + mi * 16 + (lg << 2) + r;
                out[(size_t)row * F_ + col] = acc[mi][ni][r] + bv;
            }
        }
    }
}

// ---------- attention 32x32 tile: NO-MAX softmax (R16-proven) ----------
__device__ __forceinline__ void attn_tile32(
    const unsigned short* __restrict__ k, const unsigned short* __restrict__ v,
    int bh, int jt, bool pref, bool diag, int qcol, int hi, size_t lofs,
    const bf16x8 (&qf)[4], bf16x8 (&kcur)[4], bf16x8 (&knxt)[4],
    float &lsum, f32x16 &ot0, f32x16 &ot1)
{
    bf16x8 vf[4];
    const unsigned short* vp = v + (size_t)(bh * 64 + jt) * 2048 + lofs;
#pragma unroll
    for (int i = 0; i < 4; ++i)
        vf[i] = *reinterpret_cast<const bf16x8*>(vp + i * 512);
    if (pref) {
        const unsigned short* kp = k + (size_t)(bh * 64 + jt + 1) * 2048 + lofs;
#pragma unroll
        for (int kf = 0; kf < 4; ++kf)
            knxt[kf] = *reinterpret_cast<const bf16x8*>(kp + kf * 512);
    }

    f32x16 st = {};
#pragma unroll
    for (int kf = 0; kf < 4; ++kf)
        st = __builtin_amdgcn_mfma_f32_32x32x16_bf16(kcur[kf], qf[kf], st, 0, 0, 0);

    if (diag) {
        int qmh = qcol - 4 * hi;
#pragma unroll
        for (int r = 0; r < 16; ++r) {
            const int kbase = (r & 3) + 8 * (r >> 2);
            st[r] = (kbase > qmh) ? -1e30f : st[r];
        }
    }

    float ps = 0.f;
#pragma unroll
    for (int r = 0; r < 16; ++r) { st[r] = exp2f(st[r]); ps += st[r]; }
    lsum += ps;

    U8 pa0, pa1;
#pragma unroll
    for (int f = 0; f < 2; ++f) {
        unsigned int a0 = cvtpk_bf16(st[f * 8 + 0], st[f * 8 + 1]);
        unsigned int b0 = cvtpk_bf16(st[f * 8 + 4], st[f * 8 + 5]);
        asm("v_permlane32_swap_b32 %0, %1" : "+v"(a0), "+v"(b0));
        unsigned int a1 = cvtpk_bf16(st[f * 8 + 2], st[f * 8 + 3]);
        unsigned int b1 = cvtpk_bf16(st[f * 8 + 6], st[f * 8 + 7]);
        asm("v_permlane32_swap_b32 %0, %1" : "+v"(a1), "+v"(b1));
        U8& pa = f ? pa1 : pa0;
        pa.u[0] = a0; pa.u[1] = a1; pa.u[2] = b0; pa.u[3] = b1;
    }

    ot0 = __builtin_amdgcn_mfma_f32_32x32x16_bf16(vf[0], pa0.v, ot0, 0, 0, 0);
    ot0 = __builtin_amdgcn_mfma_f32_32x32x16_bf16(vf[1], pa1.v, ot0, 0, 0, 0);
    ot1 = __builtin_amdgcn_mfma_f32_32x32x16_bf16(vf[2], pa0.v, ot1, 0, 0, 0);
    ot1 = __builtin_amdgcn_mfma_f32_32x32x16_bf16(vf[3], pa1.v, ot1, 0, 0, 0);
}

// ---------- causal flash attention: 4-wave block, 4-way split-K, pure-sum merge ----------
// (256,3): live set ~120-130 VGPR needs the ~170 cap. THREE measured spill regressions
// (R5, R17, R19) prove any +32-VGPR structural change or higher occupancy bound spills.
__global__ __launch_bounds__(256, 3) void attn_kernel(const unsigned short* __restrict__ q,
                                                      const unsigned short* __restrict__ k,
                                                      const unsigned short* __restrict__ v,
                                                      unsigned short* __restrict__ z) {
    __shared__ __align__(16) float mbuf[3][64][36];
    int bh = blockIdx.x;
    int qt = gridDim.y - 1 - blockIdx.y;
    int q0 = qt << 5;
    int tid = threadIdx.x, w = tid >> 6, l = tid & 63;
    int qcol = l & 31, hi = l >> 5;
    size_t lofs = (size_t)l * 8;

    bf16x8 qf[4];
    {
        const unsigned short* qp = q + (size_t)(bh * 64 + qt) * 2048 + lofs;
#pragma unroll
        for (int kf = 0; kf < 4; ++kf)
            qf[kf] = *reinterpret_cast<const bf16x8*>(qp + kf * 512);
    }

    f32x16 ot0 = {}, ot1 = {};
    float lsum = 0.f;

    int ntk = qt + 1;
    int bs = ntk >> 2, rem = ntk & 3;
    int cnt = bs + ((w >= 4 - rem) ? 1 : 0);
    int start = bs * w + ((w - (4 - rem)) > 0 ? (w - (4 - rem)) : 0);
    int end = start + cnt;

    if (cnt > 0) {
        bf16x8 kA[4], kB[4];
        const unsigned short* kp = k + (size_t)(bh * 64 + start) * 2048 + lofs;
#pragma unroll
        for (int kf = 0; kf < 4; ++kf)
            kA[kf] = *reinterpret_cast<const bf16x8*>(kp + kf * 512);

        int jt = start;
        for (;;) {
            attn_tile32(k, v, bh, jt, jt + 1 < end, jt == qt, qcol, hi, lofs,
                        qf, kA, kB, lsum, ot0, ot1);
            if (++jt >= end) break;
            attn_tile32(k, v, bh, jt, jt + 1 < end, jt == qt, qcol, hi, lofs,
                        qf, kB, kA, lsum, ot0, ot1);
            if (++jt >= end) break;
        }
    }

    lsum = xhalf_sum(lsum);

    if (w) {
        float* row = mbuf[w - 1][l];
        row[0] = lsum;
        *reinterpret_cast<f32x16*>(&row[4]) = ot0;
        *reinterpret_cast<f32x16*>(&row[20]) = ot1;
    }
    __syncthreads();
    if (w == 0) {
#pragma unroll
        for (int i = 0; i < 3; ++i) {
            lsum += mbuf[i][l][0];
            f32x16 t0 = *reinterpret_cast<const f32x16*>(&mbuf[i][l][4]);
            f32x16 t1 = *reinterpret_cast<const f32x16*>(&mbuf[i][l][20]);
            ot0 += t0;
            ot1 += t1;
        }

        float inv = 1.0f / lsum;
        int b = bh >> 4, h = bh & 15;
        size_t zrow = ((size_t)(b * S_ + q0 + qcol)) * F_ + h * D_;
#pragma unroll
        for (int db = 0; db < 2; ++db) {
#pragma unroll
            for (int rq = 0; rq < 4; ++rq) {
                ushort4 pk;
                unsigned short* pp = reinterpret_cast<unsigned short*>(&pk);
#pragma unroll
                for (int i = 0; i < 4; ++i) {
                    float val = (db == 0 ? ot0[rq * 4 + i] : ot1[rq * 4 + i]) * inv;
                    pp[i] = f2bf(val);
                }
                *reinterpret_cast<ushort4*>(&z[zrow + db * 32 + rq * 8 + hi * 4]) = pk;
            }
        }
    }
}

extern "C" void kernel_launch(void* const* d_in, const int* in_sizes, int n_in,
                              void* d_out, int out_size, void* d_ws, size_t ws_size,
                              hipStream_t stream) {
    const float* x      = (const float*)d_in[0];
    const float* w_attn = (const float*)d_in[1];
    const float* b_attn = (const float*)d_in[2];
    const float* w_proj = (const float*)d_in[3];
    const float* b_proj = (const float*)d_in[4];
    float* out = (float*)d_out;
    char* ws = (char*)d_ws;

    unsigned short* xb   = (unsigned short*)(ws);              // [4096][1024] bf16, reused as z
    unsigned short* wa_t = (unsigned short*)(ws + 8388608);    // [3072][1024]
    unsigned short* wp_t = (unsigned short*)(ws + 14680064);   // [1024][1024]
    unsigned short* qb   = (unsigned short*)(ws + 16777216);   // fragment-major Q (pre-scaled)
    unsigned short* kb   = (unsigned short*)(ws + 25165824);   // fragment-major K
    unsigned short* vb   = (unsigned short*)(ws + 33554432);   // fragment-major V
    unsigned short* zb   = xb;                                 // alias: x consumed by gemm_qkv

    prep_kernel<<<8192, 256, 0, stream>>>(x, xb, w_attn, wa_t, w_proj, wp_t);
    gemm_qkv<<<192, 512, 0, stream>>>(xb, wa_t, b_attn, qb, kb, vb);
    attn_kernel<<<dim3(32, 64), 256, 0, stream>>>(qb, kb, vb, zb);
    gemm_proj<<<dim3(8, 32), 256, 0, stream>>>(zb, wp_t, b_proj, out);
}